// Round 4
// baseline (179.688 us; speedup 1.0000x reference)
//
#include <hip/hip_runtime.h>
#include <math.h>

// Problem constants
#define B_ 2
#define S_ 8193
#define L_ 8192
#define E_ 512
#define H_ 8
#define D_ 64
#define QKV_COLS 1536   // 3*E
#define SCALE 0.125f
#define M_ROWS 16386    // B*S
#define M_PAD 16512     // round up to 128

typedef unsigned short u16;
typedef __attribute__((ext_vector_type(8))) short bf16x8;
typedef __attribute__((ext_vector_type(8))) unsigned short u16x8;
typedef __attribute__((ext_vector_type(4))) float f32x4;

__device__ __forceinline__ u16 f2bf(float f) {
    unsigned u = __float_as_uint(f);
    unsigned r = (u + 0x7fffu + ((u >> 16) & 1u)) >> 16;   // RNE
    return (u16)r;
}
__device__ __forceinline__ float bf2f(u16 h) {
    return __uint_as_float((unsigned)h << 16);
}

__device__ __forceinline__ void gload_lds16(const void* g, void* l) {
    __builtin_amdgcn_global_load_lds(
        (const __attribute__((address_space(1))) void*)g,
        (__attribute__((address_space(3))) void*)l, 16, 0, 0);
}

// ---------------------------------------------------------------------------
// float -> bf16 conversion, 512 cols, zero-pads rows >= rows.
// ---------------------------------------------------------------------------
__global__ __launch_bounds__(256) void convert_bf16_512(
    const float* __restrict__ src, u16* __restrict__ dst, int rows, long total4)
{
    const long i = (long)blockIdx.x * 256 + threadIdx.x;
    if (i >= total4) return;
    const long f = i * 4;
    const long row = f >> 9;
    ushort4 o;
    if (row < rows) {
        const float4 v = *(const float4*)(src + f);
        o.x = f2bf(v.x); o.y = f2bf(v.y); o.z = f2bf(v.z); o.w = f2bf(v.w);
    } else {
        o = make_ushort4(0, 0, 0, 0);
    }
    *(ushort4*)(dst + f) = o;
}

// ---------------------------------------------------------------------------
// RoPE cos/sin table: tab[bl*32 + p2] = {cos, sin} of coord(bl, axis)/1e5 *
// 10000^(-(p2&15)/16).   grid covers B_*L_*32 threads exactly.
// ---------------------------------------------------------------------------
__global__ __launch_bounds__(256) void rope_table_kernel(
    const int* __restrict__ coords, float2* __restrict__ tab)
{
    const int i = blockIdx.x * 256 + threadIdx.x;   // bl*32 + p2
    const int p2 = i & 31;
    const int bl = i >> 5;
    const float coord = (float)coords[(size_t)bl * 2 + (p2 >> 4)] * 1e-5f;
    const float inv = exp2f(-0.83048202372184f * (float)(p2 & 15));
    float sn, cs;
    __sincosf(coord * inv, &sn, &cs);
    tab[i] = make_float2(cs, sn);
}

// ---------------------------------------------------------------------------
// bf16 MFMA GEMM: C = A @ W^T + bias.
// MODE 0: C fp32, plain.   MODE 1: C bf16, fused RoPE-2D (table) on q/k rows.
// 128x128 tile, BK=32, 4 waves (2x2), wave = 64x64 = 4x4 16x16x32 frags.
// Bijective XCD-chunked blockIdx swizzle (m204).
// ---------------------------------------------------------------------------
template <int MODE>
__global__ __launch_bounds__(256) void gemm_bf16_mfma(
    const u16* __restrict__ A, const u16* __restrict__ W,
    const float* __restrict__ bias, void* __restrict__ Cv,
    const float2* __restrict__ tab, int M, int N, int K)
{
    __shared__ u16 As[128 * 32];
    __shared__ u16 Bs[128 * 32];

    // XCD-aware bijective swizzle
    const int nwg = gridDim.x * gridDim.y;
    const int orig = blockIdx.y * gridDim.x + blockIdx.x;
    const int qq = nwg >> 3, rr = nwg & 7;
    const int xcd = orig & 7, off = orig >> 3;
    const int wgid = (xcd < rr ? xcd * (qq + 1) : rr * (qq + 1) + (xcd - rr) * qq) + off;
    const int m0 = (wgid / gridDim.x) * 128;
    const int n0 = (wgid % gridDim.x) * 128;

    const int tid  = threadIdx.x;
    const int wid  = tid >> 6;
    const int lane = tid & 63;
    const int wm = (wid >> 1) * 64;
    const int wn = (wid & 1) * 64;

    const int srow = lane >> 2;
    const int scol = (lane & 3) * 8;
    const int fr = lane & 15;
    const int fq = lane >> 4;

    f32x4 acc[4][4] = {};

    for (int k0 = 0; k0 < K; k0 += 32) {
        #pragma unroll
        for (int i = 0; i < 2; ++i) {
            const int c = wid * 2 + i;
            const int row = c * 16 + srow;
            gload_lds16(A + (size_t)(m0 + row) * K + k0 + scol, As + c * 16 * 32);
            gload_lds16(W + (size_t)(n0 + row) * K + k0 + scol, Bs + c * 16 * 32);
        }
        __syncthreads();

        bf16x8 a[4], b[4];
        #pragma unroll
        for (int mi = 0; mi < 4; ++mi)
            a[mi] = *(const bf16x8*)(As + (wm + mi * 16 + fr) * 32 + fq * 8);
        #pragma unroll
        for (int ni = 0; ni < 4; ++ni)
            b[ni] = *(const bf16x8*)(Bs + (wn + ni * 16 + fr) * 32 + fq * 8);
        #pragma unroll
        for (int mi = 0; mi < 4; ++mi)
            #pragma unroll
            for (int ni = 0; ni < 4; ++ni)
                acc[mi][ni] = __builtin_amdgcn_mfma_f32_16x16x32_bf16(
                    a[mi], b[ni], acc[mi][ni], 0, 0, 0);
        __syncthreads();
    }

    if (MODE == 0) {
        float* C = (float*)Cv;
        #pragma unroll
        for (int mi = 0; mi < 4; ++mi)
            #pragma unroll
            for (int j = 0; j < 4; ++j) {
                const int gm = m0 + wm + mi * 16 + fq * 4 + j;
                if (gm >= M) continue;
                #pragma unroll
                for (int ni = 0; ni < 4; ++ni) {
                    const int gn = n0 + wn + ni * 16 + fr;
                    C[(size_t)gm * N + gn] = acc[mi][ni][j] + bias[gn];
                }
            }
    } else {
        u16* C = (u16*)Cv;
        const bool rope_blk = (n0 < 2 * E_);   // q or k column tiles
        #pragma unroll
        for (int mi = 0; mi < 4; ++mi) {
            #pragma unroll
            for (int j = 0; j < 4; ++j) {
                const int gm = m0 + wm + mi * 16 + fq * 4 + j;
                const bool mok = gm < M;
                int b = 0, s = gm;
                if (gm >= S_) { b = 1; s = gm - S_; }
                const bool rot = rope_blk && mok && (s > 0);
                const float2* trow = tab + ((size_t)(b * L_ + (s - 1)) << 5);
                #pragma unroll
                for (int ni = 0; ni < 4; ++ni) {
                    const int gn = n0 + wn + ni * 16 + fr;
                    float v = acc[mi][ni][j] + bias[gn];
                    const float partner = __shfl_xor(v, 1, 64);  // gn^1 lives in lane^1
                    if (rot) {
                        const float2 t = trow[(gn & 63) >> 1];
                        v = (gn & 1) ? (v * t.x + partner * t.y)
                                     : (v * t.x - partner * t.y);
                    }
                    if (mok) C[(size_t)gm * N + gn] = f2bf(v);
                }
            }
        }
    }
}

// ---------------------------------------------------------------------------
// CLS attention stage 1 (bf16 qkv): flash over S chunks.
// ---------------------------------------------------------------------------
#define NCHUNK 64
#define CLS_ROWS 129   // ceil(8193/64)

__global__ __launch_bounds__(256) void cls_attn_stage1(
    const u16* __restrict__ qkvb, float* __restrict__ part)
{
    const int blk = blockIdx.x;
    const int bh = blk >> 6, ch = blk & 63;
    const int b = bh >> 3, h = bh & 7;
    const int wid = threadIdx.x >> 6, lane = threadIdx.x & 63;
    const size_t base = (size_t)b * S_ * QKV_COLS;

    const float q = bf2f(qkvb[base + h * D_ + lane]);

    const int lo = ch * CLS_ROWS;
    const int hi = (lo + CLS_ROWS < S_) ? lo + CLS_ROWS : S_;

    float m = -1e30f, lsum = 0.f, acc = 0.f;
    for (int j = lo + wid; j < hi; j += 4) {
        const size_t roff = base + (size_t)j * QKV_COLS;
        float t = q * bf2f(qkvb[roff + E_ + h * D_ + lane]);
        #pragma unroll
        for (int o = 32; o; o >>= 1) t += __shfl_xor(t, o, 64);
        t *= SCALE;
        const float mn = fmaxf(m, t);
        const float corr = __expf(m - mn);
        const float p = __expf(t - mn);
        lsum = lsum * corr + p;
        acc = acc * corr + p * bf2f(qkvb[roff + 2 * E_ + h * D_ + lane]);
        m = mn;
    }

    __shared__ float sm[4], sl[4], sacc[4][64];
    if (lane == 0) { sm[wid] = m; sl[wid] = lsum; }
    sacc[wid][lane] = acc;
    __syncthreads();
    if (wid == 0) {
        const float gm = fmaxf(fmaxf(sm[0], sm[1]), fmaxf(sm[2], sm[3]));
        float gl = 0.f, ga = 0.f;
        #pragma unroll
        for (int w = 0; w < 4; ++w) {
            const float c = __expf(sm[w] - gm);
            gl += sl[w] * c;
            ga += sacc[w][lane] * c;
        }
        float* pp = part + ((size_t)bh * NCHUNK + ch) * 66;
        if (lane == 0) { pp[0] = gm; pp[1] = gl; }
        pp[2 + lane] = ga;
    }
}

__global__ __launch_bounds__(64) void cls_attn_stage2(
    const float* __restrict__ part, u16* __restrict__ attnb)
{
    const int bh = blockIdx.x;
    const int lane = threadIdx.x;
    const int b = bh >> 3, h = bh & 7;
    float gm = -1e30f;
    for (int c = 0; c < NCHUNK; ++c)
        gm = fmaxf(gm, part[((size_t)bh * NCHUNK + c) * 66]);
    float gl = 0.f, ga = 0.f;
    for (int c = 0; c < NCHUNK; ++c) {
        const float* pp = part + ((size_t)bh * NCHUNK + c) * 66;
        const float w = __expf(pp[0] - gm);
        gl += pp[1] * w;
        ga += pp[2 + lane] * w;
    }
    attnb[(size_t)(b * S_) * E_ + h * D_ + lane] = f2bf(ga / gl);
}

// ---------------------------------------------------------------------------
// Patch attention: lane = query. Block = 128 threads (2 waves) = 128 queries.
// K then V staged sequentially in one XOR-swizzled LDS buffer.
// ---------------------------------------------------------------------------
#define PQT 128

__global__ __launch_bounds__(128) void patch_attn(
    const u16* __restrict__ qkvb, u16* __restrict__ attnb)
{
    const int blk = blockIdx.x;
    const int qt = blk & 63;
    const int h = (blk >> 6) & 7;
    const int b = blk >> 9;
    const int l0 = qt * PQT;
    const size_t base = (size_t)b * S_ * QKV_COLS;
    const int hoff = h * D_;

    __shared__ u16 kv[144 * 64];
    __shared__ float kc[64], vc[64];

    const int t = threadIdx.x;

    if (t < 64) kc[t] = bf2f(qkvb[base + E_ + hoff + t]);
    else        vc[t - 64] = bf2f(qkvb[base + 2 * E_ + hoff + (t - 64)]);

    #pragma unroll
    for (int i = 0; i < 9; ++i) {
        const int ci = i * 128 + t;
        const int r = ci >> 3, c = ci & 7;
        const int lg = l0 - 8 + r;
        u16x8 v = {};
        if (lg >= 0 && lg < L_)
            v = *(const u16x8*)(qkvb + base + (size_t)(1 + lg) * QKV_COLS + E_ + hoff + c * 8);
        *(u16x8*)(kv + r * 64 + ((c ^ (r & 7)) * 8)) = v;
    }
    __syncthreads();

    const int l = l0 + t;
    const size_t qrow = base + (size_t)(1 + l) * QKV_COLS + hoff;

    float s[10];
    #pragma unroll
    for (int w = 0; w < 10; ++w) s[w] = 0.f;

    #pragma unroll
    for (int c = 0; c < 8; ++c) {
        const u16x8 qv = *(const u16x8*)(qkvb + qrow + c * 8);
        float qf[8];
        #pragma unroll
        for (int i = 0; i < 8; ++i) qf[i] = bf2f(qv[i]);
        #pragma unroll
        for (int i = 0; i < 8; ++i) s[0] += qf[i] * kc[c * 8 + i];
        #pragma unroll
        for (int w = 0; w < 9; ++w) {
            const int kr = t + 2 * w;
            const u16x8 kk = *(const u16x8*)(kv + kr * 64 + ((c ^ (kr & 7)) * 8));
            #pragma unroll
            for (int i = 0; i < 8; ++i) s[1 + w] += qf[i] * bf2f(kk[i]);
        }
    }

    s[0] *= SCALE;
    #pragma unroll
    for (int w = 0; w < 9; ++w) {
        const int lp = l + 2 * w - 8;
        s[1 + w] = (lp >= 0 && lp < L_) ? s[1 + w] * SCALE : -1e30f;
    }
    float m = s[0];
    #pragma unroll
    for (int w = 1; w < 10; ++w) m = fmaxf(m, s[w]);
    float sum = 0.f;
    #pragma unroll
    for (int w = 0; w < 10; ++w) { s[w] = __expf(s[w] - m); sum += s[w]; }
    const float rsum = 1.0f / sum;

    __syncthreads();
    #pragma unroll
    for (int i = 0; i < 9; ++i) {
        const int ci = i * 128 + t;
        const int r = ci >> 3, c = ci & 7;
        const int lg = l0 - 8 + r;
        u16x8 v = {};
        if (lg >= 0 && lg < L_)
            v = *(const u16x8*)(qkvb + base + (size_t)(1 + lg) * QKV_COLS + 2 * E_ + hoff + c * 8);
        *(u16x8*)(kv + r * 64 + ((c ^ (r & 7)) * 8)) = v;
    }
    __syncthreads();

    const size_t orow = (size_t)(b * S_ + 1 + l) * E_ + hoff;
    #pragma unroll
    for (int c = 0; c < 8; ++c) {
        float acc[8];
        #pragma unroll
        for (int i = 0; i < 8; ++i) acc[i] = s[0] * vc[c * 8 + i];
        #pragma unroll
        for (int w = 0; w < 9; ++w) {
            const int vr = t + 2 * w;
            const u16x8 vv = *(const u16x8*)(kv + vr * 64 + ((c ^ (vr & 7)) * 8));
            #pragma unroll
            for (int i = 0; i < 8; ++i) acc[i] += s[1 + w] * bf2f(vv[i]);
        }
        u16x8 o;
        #pragma unroll
        for (int i = 0; i < 8; ++i) o[i] = f2bf(acc[i] * rsum);
        *(u16x8*)(attnb + orow + c * 8) = o;
    }
}

// ---------------------------------------------------------------------------
// Launch
// ---------------------------------------------------------------------------
extern "C" void kernel_launch(void* const* d_in, const int* in_sizes, int n_in,
                              void* d_out, int out_size, void* d_ws, size_t ws_size,
                              hipStream_t stream)
{
    const float* x      = (const float*)d_in[0];
    const int*   coords = (const int*)  d_in[1];
    const float* w_qkv  = (const float*)d_in[2];
    const float* b_qkv  = (const float*)d_in[3];
    const float* w_out  = (const float*)d_in[4];
    const float* b_out  = (const float*)d_in[5];
    float* out = (float*)d_out;

    // workspace layout
    u16*   qkvb  = (u16*)d_ws;                                // M_ROWS x 1536 bf16
    u16*   xb    = qkvb + (size_t)M_ROWS * QKV_COLS;          // M_PAD x 512 bf16
    u16*   attnb = xb;                                        // alias (x dead after qkv GEMM)
    u16*   wqb   = xb + (size_t)M_PAD * E_;                   // 1536 x 512
    u16*   wob   = wqb + (size_t)QKV_COLS * E_;               // 512 x 512
    float* part  = (float*)(wob + (size_t)E_ * E_);           // 16*64*66 floats
    float2* tab  = (float2*)(part + (size_t)16 * NCHUNK * 66);// B*L*32 float2 (4 MB)

    // 1. convert inputs to bf16 + rope table
    {
        const long t4x = (long)M_PAD * E_ / 4;
        convert_bf16_512<<<(t4x + 255) / 256, 256, 0, stream>>>(x, xb, M_ROWS, t4x);
        const long t4q = (long)QKV_COLS * E_ / 4;
        convert_bf16_512<<<(t4q + 255) / 256, 256, 0, stream>>>(w_qkv, wqb, QKV_COLS, t4q);
        const long t4o = (long)E_ * E_ / 4;
        convert_bf16_512<<<(t4o + 255) / 256, 256, 0, stream>>>(w_out, wob, E_, t4o);
        rope_table_kernel<<<(B_ * L_ * 32) / 256, 256, 0, stream>>>(coords, tab);
    }

    // 2. QKV projection + fused RoPE (table), bf16 out
    {
        dim3 grid(QKV_COLS / 128, M_PAD / 128);
        gemm_bf16_mfma<1><<<grid, 256, 0, stream>>>(
            xb, wqb, b_qkv, qkvb, tab, M_ROWS, QKV_COLS, E_);
    }

    // 3. CLS attention
    cls_attn_stage1<<<B_ * H_ * NCHUNK, 256, 0, stream>>>(qkvb, part);
    cls_attn_stage2<<<B_ * H_, 64, 0, stream>>>(part, attnb);

    // 4. Patch windowed attention
    patch_attn<<<B_ * H_ * (L_ / PQT), PQT, 0, stream>>>(qkvb, attnb);

    // 5. Output projection (fp32 out)
    {
        dim3 grid(E_ / 128, M_PAD / 128);
        gemm_bf16_mfma<0><<<grid, 256, 0, stream>>>(
            attnb, wob, b_out, out, nullptr, M_ROWS, E_, E_);
    }
}